// Round 5
// baseline (524.522 us; speedup 1.0000x reference)
//
#include <hip/hip_runtime.h>

#define NN 50000
#define NE 800000

typedef float  f4v __attribute__((ext_vector_type(4)));
typedef float  f2v __attribute__((ext_vector_type(2)));

__device__ __forceinline__ int ntload_i(const int* p) {
    return __builtin_nontemporal_load(p);
}
__device__ __forceinline__ int2 ntload_i2(const int2* p) {
    unsigned long long v = __builtin_nontemporal_load((const unsigned long long*)p);
    int2 r; r.x = (int)(unsigned)v; r.y = (int)(unsigned)(v >> 32); return r;
}
__device__ __forceinline__ float4 ntload_f4(const float4* p) {
    f4v v = __builtin_nontemporal_load((const f4v*)p);
    return make_float4(v.x, v.y, v.z, v.w);
}
__device__ __forceinline__ void ntstore_f2(float2* p, float2 v) {
    f2v t; t.x = v.x; t.y = v.y;
    __builtin_nontemporal_store(t, (f2v*)p);
}
__device__ __forceinline__ void ntstore_f4(float4* p, float4 v) {
    f4v t; t.x = v.x; t.y = v.y; t.z = v.z; t.w = v.w;
    __builtin_nontemporal_store(t, (f4v*)p);
}

// ================= CSR build =================
__global__ __launch_bounds__(256) void k_deg_init(int* deg) {
    int i = blockIdx.x * 256 + threadIdx.x;
    if (i < NN) deg[i] = 0;
}

__global__ __launch_bounds__(256) void k_deg_count(const int* __restrict__ dst, int* __restrict__ deg) {
    int e = blockIdx.x * 256 + threadIdx.x;
    if (e < NE) atomicAdd(&deg[ntload_i(&dst[e])], 1);
}

__global__ __launch_bounds__(256) void k_dinv(const int* __restrict__ deg, float* __restrict__ dinv) {
    int i = blockIdx.x * 256 + threadIdx.x;
    if (i < NN) dinv[i] = rsqrtf((float)(deg[i] + 1));   // +1 = self loop
}

__global__ __launch_bounds__(256) void k_scan1(const int* __restrict__ deg, int* __restrict__ bsum) {
    __shared__ int s[256];
    int tid = threadIdx.x;
    int i = blockIdx.x * 256 + tid;
    s[tid] = (i < NN) ? deg[i] : 0;
    __syncthreads();
    for (int d = 128; d > 0; d >>= 1) {
        if (tid < d) s[tid] += s[tid + d];
        __syncthreads();
    }
    if (tid == 0) bsum[blockIdx.x] = s[0];
}

__global__ __launch_bounds__(256) void k_scan2(int* bsum, int nblocks) {
    __shared__ int s[256];
    int tid = threadIdx.x;
    int v = (tid < nblocks) ? bsum[tid] : 0;
    s[tid] = v;
    __syncthreads();
    for (int d = 1; d < 256; d <<= 1) {
        int t = (tid >= d) ? s[tid - d] : 0;
        __syncthreads();
        s[tid] += t;
        __syncthreads();
    }
    if (tid < nblocks) bsum[tid] = s[tid] - v;   // exclusive
}

__global__ __launch_bounds__(256) void k_scan3(int* __restrict__ deg, const int* __restrict__ bsum,
                                               int* __restrict__ off) {
    __shared__ int s[256];
    int tid = threadIdx.x;
    int i = blockIdx.x * 256 + tid;
    int v = (i < NN) ? deg[i] : 0;
    s[tid] = v;
    __syncthreads();
    for (int d = 1; d < 256; d <<= 1) {
        int t = (tid >= d) ? s[tid - d] : 0;
        __syncthreads();
        s[tid] += t;
        __syncthreads();
    }
    int excl = bsum[blockIdx.x] + s[tid] - v;
    if (i < NN) { off[i] = excl; deg[i] = excl; }   // deg becomes cursor
    if (i == 0) off[NN] = NE;
}

// fill CSR with (src, weight) pairs; weight = dinv[src]*dinv[dst] precomputed
__global__ __launch_bounds__(256) void k_fill(const int* __restrict__ src, const int* __restrict__ dst,
                                              const float* __restrict__ dinv,
                                              int* __restrict__ cursor, int2* __restrict__ epair) {
    int e = blockIdx.x * 256 + threadIdx.x;
    if (e >= NE) return;
    int s = ntload_i(&src[e]), d = ntload_i(&dst[e]);
    int p = atomicAdd(&cursor[d], 1);
    epair[p] = make_int2(s, __float_as_int(dinv[s] * dinv[d]));
}

// ================= GEMM: C[N,128] = X[N,128] @ W[128,128] =================
__global__ __launch_bounds__(256, 3) void k_gemm(const float* __restrict__ X,
                                                 const float* __restrict__ W,
                                                 float* __restrict__ C, int N) {
    __shared__ float Xs[2][32][64];
    __shared__ float Ws[2][32][128];
    int tid  = threadIdx.x;
    int row0 = blockIdx.x * 64;
    int tc = tid & 31, tr = tid >> 5;

    const float4* X4 = (const float4*)X;
    const float4* W4 = (const float4*)W;

    float acc[8][4];
#pragma unroll
    for (int i = 0; i < 8; ++i)
#pragma unroll
        for (int j = 0; j < 4; ++j) acc[i][j] = 0.f;

#define STAGE(kk, buf)                                                        \
    {                                                                         \
        _Pragma("unroll")                                                     \
        for (int i = 0; i < 2; ++i) {                                         \
            int idx = tid + i * 256;                                          \
            int r = idx >> 3, q = idx & 7;                                    \
            int gr = row0 + r;                                                \
            float4 v = (gr < N) ? ntload_f4(&X4[gr * 32 + (kk) * 8 + q])      \
                                : make_float4(0.f, 0.f, 0.f, 0.f);            \
            Xs[buf][q * 4 + 0][r] = v.x;                                      \
            Xs[buf][q * 4 + 1][r] = v.y;                                      \
            Xs[buf][q * 4 + 2][r] = v.z;                                      \
            Xs[buf][q * 4 + 3][r] = v.w;                                      \
        }                                                                     \
        _Pragma("unroll")                                                     \
        for (int i = 0; i < 4; ++i) {                                         \
            int idx = tid + i * 256;                                          \
            int k = idx >> 5, cq = idx & 31;                                  \
            float4 v = W4[((kk) * 32 + k) * 32 + cq];                         \
            *(float4*)&Ws[buf][k][cq * 4] = v;                                \
        }                                                                     \
    }

    STAGE(0, 0);
    for (int kk = 0; kk < 4; ++kk) {
        __syncthreads();
        if (kk < 3) STAGE(kk + 1, (kk + 1) & 1);
        int buf = kk & 1;
#pragma unroll 8
        for (int k = 0; k < 32; ++k) {
            float4 xa = *(const float4*)&Xs[buf][k][tr * 8];
            float4 xb = *(const float4*)&Xs[buf][k][tr * 8 + 4];
            float4 wv = *(const float4*)&Ws[buf][k][tc * 4];
            float xr[8] = {xa.x, xa.y, xa.z, xa.w, xb.x, xb.y, xb.z, xb.w};
            float wr[4] = {wv.x, wv.y, wv.z, wv.w};
#pragma unroll
            for (int i = 0; i < 8; ++i)
#pragma unroll
                for (int j = 0; j < 4; ++j) acc[i][j] += xr[i] * wr[j];
        }
    }
#undef STAGE

#pragma unroll
    for (int i = 0; i < 8; ++i) {
        int r = row0 + tr * 8 + i;
        if (r < N) {
            float4 v = make_float4(acc[i][0], acc[i][1], acc[i][2], acc[i][3]);
            *(float4*)&C[r * 128 + tc * 4] = v;
        }
    }
}

// ================= final: [mu | lv] = X @ [Wmu|Wlv] + [bmu|blv], packed out =================
__global__ __launch_bounds__(256, 3) void k_final(const float* __restrict__ X,
                                                  const float4* __restrict__ Wmu4, const float* __restrict__ bmu,
                                                  const float4* __restrict__ Wlv4, const float* __restrict__ blv,
                                                  float* __restrict__ out, int N) {
    __shared__ float Xs[2][32][64];
    __shared__ float Ws[2][32][128];
    int tid  = threadIdx.x;
    int row0 = blockIdx.x * 64;
    int tc = tid & 31, tr = tid >> 5;

    const float4* X4 = (const float4*)X;

    float acc[8][4];
#pragma unroll
    for (int i = 0; i < 8; ++i)
#pragma unroll
        for (int j = 0; j < 4; ++j) acc[i][j] = 0.f;

#define STAGEF(kk, buf)                                                       \
    {                                                                         \
        _Pragma("unroll")                                                     \
        for (int i = 0; i < 2; ++i) {                                         \
            int idx = tid + i * 256;                                          \
            int r = idx >> 3, q = idx & 7;                                    \
            int gr = row0 + r;                                                \
            float4 v = (gr < N) ? ntload_f4(&X4[gr * 32 + (kk) * 8 + q])      \
                                : make_float4(0.f, 0.f, 0.f, 0.f);            \
            Xs[buf][q * 4 + 0][r] = v.x;                                      \
            Xs[buf][q * 4 + 1][r] = v.y;                                      \
            Xs[buf][q * 4 + 2][r] = v.z;                                      \
            Xs[buf][q * 4 + 3][r] = v.w;                                      \
        }                                                                     \
        _Pragma("unroll")                                                     \
        for (int i = 0; i < 4; ++i) {                                         \
            int idx = tid + i * 256;                                          \
            int k = idx >> 5, cq = idx & 31;                                  \
            float4 v = (cq < 16) ? Wmu4[((kk) * 32 + k) * 16 + cq]            \
                                 : Wlv4[((kk) * 32 + k) * 16 + (cq - 16)];    \
            *(float4*)&Ws[buf][k][cq * 4] = v;                                \
        }                                                                     \
    }

    STAGEF(0, 0);
    for (int kk = 0; kk < 4; ++kk) {
        __syncthreads();
        if (kk < 3) STAGEF(kk + 1, (kk + 1) & 1);
        int buf = kk & 1;
#pragma unroll 8
        for (int k = 0; k < 32; ++k) {
            float4 xa = *(const float4*)&Xs[buf][k][tr * 8];
            float4 xb = *(const float4*)&Xs[buf][k][tr * 8 + 4];
            float4 wv = *(const float4*)&Ws[buf][k][tc * 4];
            float xr[8] = {xa.x, xa.y, xa.z, xa.w, xb.x, xb.y, xb.z, xb.w};
            float wr[4] = {wv.x, wv.y, wv.z, wv.w};
#pragma unroll
            for (int i = 0; i < 8; ++i)
#pragma unroll
                for (int j = 0; j < 4; ++j) acc[i][j] += xr[i] * wr[j];
        }
    }
#undef STAGEF

    float4 bb = (tc < 16) ? *(const float4*)&bmu[tc * 4]
                          : *(const float4*)&blv[tc * 4 - 64];
#pragma unroll
    for (int i = 0; i < 8; ++i) {
        int r = row0 + tr * 8 + i;
        if (r < N) {
            float4 v = make_float4(acc[i][0] + bb.x, acc[i][1] + bb.y,
                                   acc[i][2] + bb.z, acc[i][3] + bb.w);
            if (tc < 16) ntstore_f4((float4*)&out[r * 64 + tc * 4], v);
            else         ntstore_f4((float4*)&out[(size_t)NN * 64 + r * 64 + tc * 4 - 64], v);
        }
    }
}

// ================= gather agg + self-loop + bias + relu =================
// 8 lanes/node (16 ch via float2), 32 nodes/block, chunk = blockIdx&7 (XCD slice).
// epair is streamed once per XCD -> nontemporal loads so it can't evict the
// L2-resident 3.2MB h column slice. out is consumed on other XCDs -> nt store.
__global__ __launch_bounds__(256) void k_agg(const float* __restrict__ h, const int* __restrict__ off,
                                             const int2* __restrict__ epair, const float* __restrict__ dinv,
                                             const float* __restrict__ b, float* __restrict__ out) {
    int chunk = blockIdx.x & 7;
    int g     = blockIdx.x >> 3;
    int sub   = threadIdx.x & 7;
    int n     = g * 32 + (threadIdx.x >> 3);
    if (n >= NN) return;
    int o0 = off[n], o1 = off[n + 1];
    const float2* h2 = (const float2*)h;
    int cb = chunk * 8 + sub;   // float2 index within the 64-float2 row

    float2 a0 = {0.f, 0.f}, a1 = {0.f, 0.f}, a2 = {0.f, 0.f}, a3 = {0.f, 0.f};
    int e = o0;
    for (; e + 8 <= o1; e += 8) {
        int2 p0 = ntload_i2(&epair[e + 0]), p1 = ntload_i2(&epair[e + 1]);
        int2 p2 = ntload_i2(&epair[e + 2]), p3 = ntload_i2(&epair[e + 3]);
        int2 p4 = ntload_i2(&epair[e + 4]), p5 = ntload_i2(&epair[e + 5]);
        int2 p6 = ntload_i2(&epair[e + 6]), p7 = ntload_i2(&epair[e + 7]);
        float2 v0 = h2[p0.x * 64 + cb];
        float2 v1 = h2[p1.x * 64 + cb];
        float2 v2 = h2[p2.x * 64 + cb];
        float2 v3 = h2[p3.x * 64 + cb];
        float2 v4 = h2[p4.x * 64 + cb];
        float2 v5 = h2[p5.x * 64 + cb];
        float2 v6 = h2[p6.x * 64 + cb];
        float2 v7 = h2[p7.x * 64 + cb];
        float w0 = __int_as_float(p0.y), w1 = __int_as_float(p1.y);
        float w2 = __int_as_float(p2.y), w3 = __int_as_float(p3.y);
        float w4 = __int_as_float(p4.y), w5 = __int_as_float(p5.y);
        float w6 = __int_as_float(p6.y), w7 = __int_as_float(p7.y);
        a0.x += v0.x * w0; a0.y += v0.y * w0;
        a1.x += v1.x * w1; a1.y += v1.y * w1;
        a2.x += v2.x * w2; a2.y += v2.y * w2;
        a3.x += v3.x * w3; a3.y += v3.y * w3;
        a0.x += v4.x * w4; a0.y += v4.y * w4;
        a1.x += v5.x * w5; a1.y += v5.y * w5;
        a2.x += v6.x * w6; a2.y += v6.y * w6;
        a3.x += v7.x * w7; a3.y += v7.y * w7;
    }
    if (e + 4 <= o1) {
        int2 p0 = ntload_i2(&epair[e + 0]), p1 = ntload_i2(&epair[e + 1]);
        int2 p2 = ntload_i2(&epair[e + 2]), p3 = ntload_i2(&epair[e + 3]);
        float2 v0 = h2[p0.x * 64 + cb];
        float2 v1 = h2[p1.x * 64 + cb];
        float2 v2 = h2[p2.x * 64 + cb];
        float2 v3 = h2[p3.x * 64 + cb];
        float w0 = __int_as_float(p0.y), w1 = __int_as_float(p1.y);
        float w2 = __int_as_float(p2.y), w3 = __int_as_float(p3.y);
        a0.x += v0.x * w0; a0.y += v0.y * w0;
        a1.x += v1.x * w1; a1.y += v1.y * w1;
        a2.x += v2.x * w2; a2.y += v2.y * w2;
        a3.x += v3.x * w3; a3.y += v3.y * w3;
        e += 4;
    }
    for (; e < o1; ++e) {
        int2 p = ntload_i2(&epair[e]);
        float2 v = h2[p.x * 64 + cb];
        float w = __int_as_float(p.y);
        a0.x += v.x * w; a0.y += v.y * w;
    }

    float dn = dinv[n];
    float sn = dn * dn;
    float2 hv = h2[n * 64 + cb];
    float2 bb = ((const float2*)b)[cb];
    float2 r;
    r.x = fmaxf((a0.x + a1.x) + (a2.x + a3.x) + hv.x * sn + bb.x, 0.f);
    r.y = fmaxf((a0.y + a1.y) + (a2.y + a3.y) + hv.y * sn + bb.y, 0.f);
    ntstore_f2((float2*)&out[(size_t)n * 128 + cb * 2], r);
}

extern "C" void kernel_launch(void* const* d_in, const int* in_sizes, int n_in,
                              void* d_out, int out_size, void* d_ws, size_t ws_size,
                              hipStream_t stream) {
    const float* x    = (const float*)d_in[0];
    const int*   eidx = (const int*)d_in[1];
    const float* W1   = (const float*)d_in[2];
    const float* b1   = (const float*)d_in[3];
    const float* W2   = (const float*)d_in[4];
    const float* b2   = (const float*)d_in[5];
    const float* Wmu  = (const float*)d_in[6];
    const float* bmu  = (const float*)d_in[7];
    const float* Wlv  = (const float*)d_in[8];
    const float* blv  = (const float*)d_in[9];
    float* out = (float*)d_out;

    const int* src = eidx;        // edge_index[0]
    const int* dst = eidx + NE;   // edge_index[1]

    // workspace layout (4-byte units)
    float* ws      = (float*)d_ws;
    float* dinv    = ws;                           // 50048
    int*   deg     = (int*)(ws + 50048);           // 50048 (becomes cursor)
    int*   off     = (int*)(ws + 100096);          // 50048 (N+1 used)
    int*   bsum    = (int*)(ws + 150144);          // 256
    int2*  epair   = (int2*)(ws + 150400);         // 800000 int2 (8B-aligned)
    float* H       = ws + 1750400;                 // 6.4M
    float* H2      = ws + 8150400;                 // 6.4M  (total ~58.2 MB)

    const int gN  = (NN + 255) / 256;      // 196
    const int gE  = (NE + 255) / 256;      // 3125
    const int gG  = (NN + 63) / 64;        // 782
    const int gA  = ((NN + 31) / 32) * 8;  // 12504

    // ---- CSR build + norms ----
    k_deg_init<<<gN, 256, 0, stream>>>(deg);
    k_deg_count<<<gE, 256, 0, stream>>>(dst, deg);
    k_dinv<<<gN, 256, 0, stream>>>(deg, dinv);
    k_scan1<<<gN, 256, 0, stream>>>(deg, bsum);
    k_scan2<<<1, 256, 0, stream>>>(bsum, gN);
    k_scan3<<<gN, 256, 0, stream>>>(deg, bsum, off);
    k_fill<<<gE, 256, 0, stream>>>(src, dst, dinv, deg, epair);

    // ---- conv1 ----
    k_gemm<<<gG, 256, 0, stream>>>(x, W1, H, NN);
    k_agg<<<gA, 256, 0, stream>>>(H, off, epair, dinv, b1, H2);

    // ---- conv2 ----
    k_gemm<<<gG, 256, 0, stream>>>(H2, W2, H, NN);
    k_agg<<<gA, 256, 0, stream>>>(H, off, epair, dinv, b2, H2);

    // ---- final projection ----
    k_final<<<gG, 256, 0, stream>>>(H2, (const float4*)Wmu, bmu, (const float4*)Wlv, blv, out, NN);
}

// Round 6
// 386.889 us; speedup vs baseline: 1.3557x; 1.3557x over previous
//
#include <hip/hip_runtime.h>

#define NN 50000
#define NE 800000

// ================= CSR build =================
__global__ __launch_bounds__(256) void k_deg_init(int* deg) {
    int i = blockIdx.x * 256 + threadIdx.x;
    if (i < NN) deg[i] = 0;
}

__global__ __launch_bounds__(256) void k_deg_count(const int* __restrict__ dst, int* __restrict__ deg) {
    int e = blockIdx.x * 256 + threadIdx.x;
    if (e < NE) atomicAdd(&deg[dst[e]], 1);
}

__global__ __launch_bounds__(256) void k_dinv(const int* __restrict__ deg, float* __restrict__ dinv) {
    int i = blockIdx.x * 256 + threadIdx.x;
    if (i < NN) dinv[i] = rsqrtf((float)(deg[i] + 1));   // +1 = self loop
}

__global__ __launch_bounds__(256) void k_scan1(const int* __restrict__ deg, int* __restrict__ bsum) {
    __shared__ int s[256];
    int tid = threadIdx.x;
    int i = blockIdx.x * 256 + tid;
    s[tid] = (i < NN) ? deg[i] : 0;
    __syncthreads();
    for (int d = 128; d > 0; d >>= 1) {
        if (tid < d) s[tid] += s[tid + d];
        __syncthreads();
    }
    if (tid == 0) bsum[blockIdx.x] = s[0];
}

__global__ __launch_bounds__(256) void k_scan2(int* bsum, int nblocks) {
    __shared__ int s[256];
    int tid = threadIdx.x;
    int v = (tid < nblocks) ? bsum[tid] : 0;
    s[tid] = v;
    __syncthreads();
    for (int d = 1; d < 256; d <<= 1) {
        int t = (tid >= d) ? s[tid - d] : 0;
        __syncthreads();
        s[tid] += t;
        __syncthreads();
    }
    if (tid < nblocks) bsum[tid] = s[tid] - v;   // exclusive
}

__global__ __launch_bounds__(256) void k_scan3(int* __restrict__ deg, const int* __restrict__ bsum,
                                               int* __restrict__ off) {
    __shared__ int s[256];
    int tid = threadIdx.x;
    int i = blockIdx.x * 256 + tid;
    int v = (i < NN) ? deg[i] : 0;
    s[tid] = v;
    __syncthreads();
    for (int d = 1; d < 256; d <<= 1) {
        int t = (tid >= d) ? s[tid - d] : 0;
        __syncthreads();
        s[tid] += t;
        __syncthreads();
    }
    int excl = bsum[blockIdx.x] + s[tid] - v;
    if (i < NN) { off[i] = excl; deg[i] = excl; }   // deg becomes cursor
    if (i == 0) off[NN] = NE;
}

// fill CSR with (src, weight) pairs; weight = dinv[src]*dinv[dst] precomputed
__global__ __launch_bounds__(256) void k_fill(const int* __restrict__ src, const int* __restrict__ dst,
                                              const float* __restrict__ dinv,
                                              int* __restrict__ cursor, int2* __restrict__ epair) {
    int e = blockIdx.x * 256 + threadIdx.x;
    if (e >= NE) return;
    int s = src[e], d = dst[e];
    int p = atomicAdd(&cursor[d], 1);
    epair[p] = make_int2(s, __float_as_int(dinv[s] * dinv[d]));
}

// ================= GEMM: C[N,128] = X[N,128] @ W[128,128] =================
__global__ __launch_bounds__(256, 3) void k_gemm(const float* __restrict__ X,
                                                 const float* __restrict__ W,
                                                 float* __restrict__ C, int N) {
    __shared__ float Xs[2][32][64];
    __shared__ float Ws[2][32][128];
    int tid  = threadIdx.x;
    int row0 = blockIdx.x * 64;
    int tc = tid & 31, tr = tid >> 5;

    const float4* X4 = (const float4*)X;
    const float4* W4 = (const float4*)W;

    float acc[8][4];
#pragma unroll
    for (int i = 0; i < 8; ++i)
#pragma unroll
        for (int j = 0; j < 4; ++j) acc[i][j] = 0.f;

#define STAGE(kk, buf)                                                        \
    {                                                                         \
        _Pragma("unroll")                                                     \
        for (int i = 0; i < 2; ++i) {                                         \
            int idx = tid + i * 256;                                          \
            int r = idx >> 3, q = idx & 7;                                    \
            int gr = row0 + r;                                                \
            float4 v = (gr < N) ? X4[gr * 32 + (kk) * 8 + q]                  \
                                : make_float4(0.f, 0.f, 0.f, 0.f);            \
            Xs[buf][q * 4 + 0][r] = v.x;                                      \
            Xs[buf][q * 4 + 1][r] = v.y;                                      \
            Xs[buf][q * 4 + 2][r] = v.z;                                      \
            Xs[buf][q * 4 + 3][r] = v.w;                                      \
        }                                                                     \
        _Pragma("unroll")                                                     \
        for (int i = 0; i < 4; ++i) {                                         \
            int idx = tid + i * 256;                                          \
            int k = idx >> 5, cq = idx & 31;                                  \
            float4 v = W4[((kk) * 32 + k) * 32 + cq];                         \
            *(float4*)&Ws[buf][k][cq * 4] = v;                                \
        }                                                                     \
    }

    STAGE(0, 0);
    for (int kk = 0; kk < 4; ++kk) {
        __syncthreads();
        if (kk < 3) STAGE(kk + 1, (kk + 1) & 1);
        int buf = kk & 1;
#pragma unroll 8
        for (int k = 0; k < 32; ++k) {
            float4 xa = *(const float4*)&Xs[buf][k][tr * 8];
            float4 xb = *(const float4*)&Xs[buf][k][tr * 8 + 4];
            float4 wv = *(const float4*)&Ws[buf][k][tc * 4];
            float xr[8] = {xa.x, xa.y, xa.z, xa.w, xb.x, xb.y, xb.z, xb.w};
            float wr[4] = {wv.x, wv.y, wv.z, wv.w};
#pragma unroll
            for (int i = 0; i < 8; ++i)
#pragma unroll
                for (int j = 0; j < 4; ++j) acc[i][j] += xr[i] * wr[j];
        }
    }
#undef STAGE

#pragma unroll
    for (int i = 0; i < 8; ++i) {
        int r = row0 + tr * 8 + i;
        if (r < N) {
            float4 v = make_float4(acc[i][0], acc[i][1], acc[i][2], acc[i][3]);
            *(float4*)&C[r * 128 + tc * 4] = v;
        }
    }
}

// ================= final: [mu | lv] = X @ [Wmu|Wlv] + [bmu|blv], packed out =================
__global__ __launch_bounds__(256, 3) void k_final(const float* __restrict__ X,
                                                  const float4* __restrict__ Wmu4, const float* __restrict__ bmu,
                                                  const float4* __restrict__ Wlv4, const float* __restrict__ blv,
                                                  float* __restrict__ out, int N) {
    __shared__ float Xs[2][32][64];
    __shared__ float Ws[2][32][128];
    int tid  = threadIdx.x;
    int row0 = blockIdx.x * 64;
    int tc = tid & 31, tr = tid >> 5;

    const float4* X4 = (const float4*)X;

    float acc[8][4];
#pragma unroll
    for (int i = 0; i < 8; ++i)
#pragma unroll
        for (int j = 0; j < 4; ++j) acc[i][j] = 0.f;

#define STAGEF(kk, buf)                                                       \
    {                                                                         \
        _Pragma("unroll")                                                     \
        for (int i = 0; i < 2; ++i) {                                         \
            int idx = tid + i * 256;                                          \
            int r = idx >> 3, q = idx & 7;                                    \
            int gr = row0 + r;                                                \
            float4 v = (gr < N) ? X4[gr * 32 + (kk) * 8 + q]                  \
                                : make_float4(0.f, 0.f, 0.f, 0.f);            \
            Xs[buf][q * 4 + 0][r] = v.x;                                      \
            Xs[buf][q * 4 + 1][r] = v.y;                                      \
            Xs[buf][q * 4 + 2][r] = v.z;                                      \
            Xs[buf][q * 4 + 3][r] = v.w;                                      \
        }                                                                     \
        _Pragma("unroll")                                                     \
        for (int i = 0; i < 4; ++i) {                                         \
            int idx = tid + i * 256;                                          \
            int k = idx >> 5, cq = idx & 31;                                  \
            float4 v = (cq < 16) ? Wmu4[((kk) * 32 + k) * 16 + cq]            \
                                 : Wlv4[((kk) * 32 + k) * 16 + (cq - 16)];    \
            *(float4*)&Ws[buf][k][cq * 4] = v;                                \
        }                                                                     \
    }

    STAGEF(0, 0);
    for (int kk = 0; kk < 4; ++kk) {
        __syncthreads();
        if (kk < 3) STAGEF(kk + 1, (kk + 1) & 1);
        int buf = kk & 1;
#pragma unroll 8
        for (int k = 0; k < 32; ++k) {
            float4 xa = *(const float4*)&Xs[buf][k][tr * 8];
            float4 xb = *(const float4*)&Xs[buf][k][tr * 8 + 4];
            float4 wv = *(const float4*)&Ws[buf][k][tc * 4];
            float xr[8] = {xa.x, xa.y, xa.z, xa.w, xb.x, xb.y, xb.z, xb.w};
            float wr[4] = {wv.x, wv.y, wv.z, wv.w};
#pragma unroll
            for (int i = 0; i < 8; ++i)
#pragma unroll
                for (int j = 0; j < 4; ++j) acc[i][j] += xr[i] * wr[j];
        }
    }
#undef STAGEF

    float4 bb = (tc < 16) ? *(const float4*)&bmu[tc * 4]
                          : *(const float4*)&blv[tc * 4 - 64];
#pragma unroll
    for (int i = 0; i < 8; ++i) {
        int r = row0 + tr * 8 + i;
        if (r < N) {
            float4 v = make_float4(acc[i][0] + bb.x, acc[i][1] + bb.y,
                                   acc[i][2] + bb.z, acc[i][3] + bb.w);
            if (tc < 16) *(float4*)&out[r * 64 + tc * 4] = v;
            else         *(float4*)&out[(size_t)NN * 64 + r * 64 + tc * 4 - 64] = v;
        }
    }
}

// ================= gather agg + self-loop + bias + relu =================
// 1 wave per node (64 lanes, float2 each = 128 ch). Edge loop = exactly deg(n):
// no divergence waste. epair read once total, wave-uniform (readfirstlane ->
// scalar loads, off the vector-memory path). Each gather = 512B contiguous
// row = 4 aligned 128B lines. 8-deep unroll for gather concurrency.
__global__ __launch_bounds__(256) void k_agg(const float* __restrict__ h, const int* __restrict__ off,
                                             const int2* __restrict__ epair, const float* __restrict__ dinv,
                                             const float* __restrict__ b, float* __restrict__ out) {
    int lane = threadIdx.x & 63;
    int n = blockIdx.x * 4 + (threadIdx.x >> 6);   // grid = 12500 -> n < 50000
    int o0 = __builtin_amdgcn_readfirstlane(off[n]);
    int o1 = __builtin_amdgcn_readfirstlane(off[n + 1]);
    const float2* h2 = (const float2*)h;

    float2 a0 = {0.f, 0.f}, a1 = {0.f, 0.f}, a2 = {0.f, 0.f}, a3 = {0.f, 0.f};
    int e = o0;
    for (; e + 8 <= o1; e += 8) {
        int s0 = __builtin_amdgcn_readfirstlane(epair[e + 0].x);
        int s1 = __builtin_amdgcn_readfirstlane(epair[e + 1].x);
        int s2 = __builtin_amdgcn_readfirstlane(epair[e + 2].x);
        int s3 = __builtin_amdgcn_readfirstlane(epair[e + 3].x);
        int s4 = __builtin_amdgcn_readfirstlane(epair[e + 4].x);
        int s5 = __builtin_amdgcn_readfirstlane(epair[e + 5].x);
        int s6 = __builtin_amdgcn_readfirstlane(epair[e + 6].x);
        int s7 = __builtin_amdgcn_readfirstlane(epair[e + 7].x);
        float w0 = __int_as_float(__builtin_amdgcn_readfirstlane(epair[e + 0].y));
        float w1 = __int_as_float(__builtin_amdgcn_readfirstlane(epair[e + 1].y));
        float w2 = __int_as_float(__builtin_amdgcn_readfirstlane(epair[e + 2].y));
        float w3 = __int_as_float(__builtin_amdgcn_readfirstlane(epair[e + 3].y));
        float w4 = __int_as_float(__builtin_amdgcn_readfirstlane(epair[e + 4].y));
        float w5 = __int_as_float(__builtin_amdgcn_readfirstlane(epair[e + 5].y));
        float w6 = __int_as_float(__builtin_amdgcn_readfirstlane(epair[e + 6].y));
        float w7 = __int_as_float(__builtin_amdgcn_readfirstlane(epair[e + 7].y));
        float2 v0 = h2[s0 * 64 + lane];
        float2 v1 = h2[s1 * 64 + lane];
        float2 v2 = h2[s2 * 64 + lane];
        float2 v3 = h2[s3 * 64 + lane];
        float2 v4 = h2[s4 * 64 + lane];
        float2 v5 = h2[s5 * 64 + lane];
        float2 v6 = h2[s6 * 64 + lane];
        float2 v7 = h2[s7 * 64 + lane];
        a0.x += v0.x * w0; a0.y += v0.y * w0;
        a1.x += v1.x * w1; a1.y += v1.y * w1;
        a2.x += v2.x * w2; a2.y += v2.y * w2;
        a3.x += v3.x * w3; a3.y += v3.y * w3;
        a0.x += v4.x * w4; a0.y += v4.y * w4;
        a1.x += v5.x * w5; a1.y += v5.y * w5;
        a2.x += v6.x * w6; a2.y += v6.y * w6;
        a3.x += v7.x * w7; a3.y += v7.y * w7;
    }
    if (e + 4 <= o1) {
        int s0 = __builtin_amdgcn_readfirstlane(epair[e + 0].x);
        int s1 = __builtin_amdgcn_readfirstlane(epair[e + 1].x);
        int s2 = __builtin_amdgcn_readfirstlane(epair[e + 2].x);
        int s3 = __builtin_amdgcn_readfirstlane(epair[e + 3].x);
        float w0 = __int_as_float(__builtin_amdgcn_readfirstlane(epair[e + 0].y));
        float w1 = __int_as_float(__builtin_amdgcn_readfirstlane(epair[e + 1].y));
        float w2 = __int_as_float(__builtin_amdgcn_readfirstlane(epair[e + 2].y));
        float w3 = __int_as_float(__builtin_amdgcn_readfirstlane(epair[e + 3].y));
        float2 v0 = h2[s0 * 64 + lane];
        float2 v1 = h2[s1 * 64 + lane];
        float2 v2 = h2[s2 * 64 + lane];
        float2 v3 = h2[s3 * 64 + lane];
        a0.x += v0.x * w0; a0.y += v0.y * w0;
        a1.x += v1.x * w1; a1.y += v1.y * w1;
        a2.x += v2.x * w2; a2.y += v2.y * w2;
        a3.x += v3.x * w3; a3.y += v3.y * w3;
        e += 4;
    }
    for (; e < o1; ++e) {
        int s0 = __builtin_amdgcn_readfirstlane(epair[e].x);
        float w0 = __int_as_float(__builtin_amdgcn_readfirstlane(epair[e].y));
        float2 v0 = h2[s0 * 64 + lane];
        a0.x += v0.x * w0; a0.y += v0.y * w0;
    }

    float dn = dinv[n];
    float sn = dn * dn;
    float2 hv = h2[n * 64 + lane];
    float2 bb = ((const float2*)b)[lane];
    float2 r;
    r.x = fmaxf((a0.x + a1.x) + (a2.x + a3.x) + hv.x * sn + bb.x, 0.f);
    r.y = fmaxf((a0.y + a1.y) + (a2.y + a3.y) + hv.y * sn + bb.y, 0.f);
    ((float2*)out)[n * 64 + lane] = r;
}

extern "C" void kernel_launch(void* const* d_in, const int* in_sizes, int n_in,
                              void* d_out, int out_size, void* d_ws, size_t ws_size,
                              hipStream_t stream) {
    const float* x    = (const float*)d_in[0];
    const int*   eidx = (const int*)d_in[1];
    const float* W1   = (const float*)d_in[2];
    const float* b1   = (const float*)d_in[3];
    const float* W2   = (const float*)d_in[4];
    const float* b2   = (const float*)d_in[5];
    const float* Wmu  = (const float*)d_in[6];
    const float* bmu  = (const float*)d_in[7];
    const float* Wlv  = (const float*)d_in[8];
    const float* blv  = (const float*)d_in[9];
    float* out = (float*)d_out;

    const int* src = eidx;        // edge_index[0]
    const int* dst = eidx + NE;   // edge_index[1]

    // workspace layout (4-byte units)
    float* ws      = (float*)d_ws;
    float* dinv    = ws;                           // 50048
    int*   deg     = (int*)(ws + 50048);           // 50048 (becomes cursor)
    int*   off     = (int*)(ws + 100096);          // 50048 (N+1 used)
    int*   bsum    = (int*)(ws + 150144);          // 256
    int2*  epair   = (int2*)(ws + 150400);         // 800000 int2 (8B-aligned)
    float* H       = ws + 1750400;                 // 6.4M
    float* H2      = ws + 8150400;                 // 6.4M

    const int gN  = (NN + 255) / 256;      // 196
    const int gE  = (NE + 255) / 256;      // 3125
    const int gG  = (NN + 63) / 64;        // 782
    const int gA  = NN / 4;                // 12500

    // ---- CSR build + norms ----
    k_deg_init<<<gN, 256, 0, stream>>>(deg);
    k_deg_count<<<gE, 256, 0, stream>>>(dst, deg);
    k_dinv<<<gN, 256, 0, stream>>>(deg, dinv);
    k_scan1<<<gN, 256, 0, stream>>>(deg, bsum);
    k_scan2<<<1, 256, 0, stream>>>(bsum, gN);
    k_scan3<<<gN, 256, 0, stream>>>(deg, bsum, off);
    k_fill<<<gE, 256, 0, stream>>>(src, dst, dinv, deg, epair);

    // ---- conv1 ----
    k_gemm<<<gG, 256, 0, stream>>>(x, W1, H, NN);
    k_agg<<<gA, 256, 0, stream>>>(H, off, epair, dinv, b1, H2);

    // ---- conv2 ----
    k_gemm<<<gG, 256, 0, stream>>>(H2, W2, H, NN);
    k_agg<<<gA, 256, 0, stream>>>(H, off, epair, dinv, b2, H2);

    // ---- final projection ----
    k_final<<<gG, 256, 0, stream>>>(H2, (const float4*)Wmu, bmu, (const float4*)Wlv, blv, out, NN);
}

// Round 7
// 330.309 us; speedup vs baseline: 1.5880x; 1.1713x over previous
//
#include <hip/hip_runtime.h>

#define NN 50000
#define NE 800000

typedef short s8v  __attribute__((ext_vector_type(8)));   // 8 bf16 (4 VGPRs)
typedef float f4v  __attribute__((ext_vector_type(4)));   // MFMA acc

__device__ __forceinline__ unsigned f2bf(float f) {       // RNE pack
    unsigned u = __float_as_uint(f);
    return (u + 0x7fffu + ((u >> 16) & 1u)) >> 16;
}
__device__ __forceinline__ float bf2f_lo(unsigned u) { return __uint_as_float(u << 16); }
__device__ __forceinline__ float bf2f_hi(unsigned u) { return __uint_as_float(u & 0xffff0000u); }

// ================= prep: cast x -> bf16 =================
__global__ __launch_bounds__(256) void k_cast_x(const float4* __restrict__ x4, uint2* __restrict__ xb) {
    int i = blockIdx.x * 256 + threadIdx.x;      // 1.6M float4s
    if (i >= NN * 32) return;
    float4 v = x4[i];
    uint2 p;
    p.x = (f2bf(v.y) << 16) | f2bf(v.x);
    p.y = (f2bf(v.w) << 16) | f2bf(v.z);
    xb[i] = p;
}

// prep: Wt[m][n][k] = W_m[k][n] as bf16.  m: 0=W1, 1=W2, 2=[Wmu|Wlv]
__global__ __launch_bounds__(256) void k_prep_w(const float* __restrict__ W1, const float* __restrict__ W2,
                                                const float* __restrict__ Wmu, const float* __restrict__ Wlv,
                                                unsigned short* __restrict__ Wt) {
    int idx = blockIdx.x * 256 + threadIdx.x;    // < 3*16384
    if (idx >= 3 * 16384) return;
    int m = idx >> 14, i = idx & 16383;
    int n = i & 127, k = i >> 7;
    float v;
    if (m == 0)      v = W1[k * 128 + n];
    else if (m == 1) v = W2[k * 128 + n];
    else             v = (n < 64) ? Wmu[k * 64 + n] : Wlv[k * 64 + (n - 64)];
    Wt[m * 16384 + n * 128 + k] = (unsigned short)f2bf(v);
}

// ================= CSR build =================
__global__ __launch_bounds__(256) void k_deg_init(int* deg) {
    int i = blockIdx.x * 256 + threadIdx.x;
    if (i < NN) deg[i] = 0;
}

__global__ __launch_bounds__(256) void k_deg_count(const int* __restrict__ dst, int* __restrict__ deg) {
    int e = blockIdx.x * 256 + threadIdx.x;
    if (e < NE) atomicAdd(&deg[dst[e]], 1);
}

__global__ __launch_bounds__(256) void k_dinv(const int* __restrict__ deg, float* __restrict__ dinv) {
    int i = blockIdx.x * 256 + threadIdx.x;
    if (i < NN) dinv[i] = rsqrtf((float)(deg[i] + 1));   // +1 = self loop
}

__global__ __launch_bounds__(256) void k_scan1(const int* __restrict__ deg, int* __restrict__ bsum) {
    __shared__ int s[256];
    int tid = threadIdx.x;
    int i = blockIdx.x * 256 + tid;
    s[tid] = (i < NN) ? deg[i] : 0;
    __syncthreads();
    for (int d = 128; d > 0; d >>= 1) {
        if (tid < d) s[tid] += s[tid + d];
        __syncthreads();
    }
    if (tid == 0) bsum[blockIdx.x] = s[0];
}

__global__ __launch_bounds__(256) void k_scan2(int* bsum, int nblocks) {
    __shared__ int s[256];
    int tid = threadIdx.x;
    int v = (tid < nblocks) ? bsum[tid] : 0;
    s[tid] = v;
    __syncthreads();
    for (int d = 1; d < 256; d <<= 1) {
        int t = (tid >= d) ? s[tid - d] : 0;
        __syncthreads();
        s[tid] += t;
        __syncthreads();
    }
    if (tid < nblocks) bsum[tid] = s[tid] - v;   // exclusive
}

__global__ __launch_bounds__(256) void k_scan3(int* __restrict__ deg, const int* __restrict__ bsum,
                                               int* __restrict__ off) {
    __shared__ int s[256];
    int tid = threadIdx.x;
    int i = blockIdx.x * 256 + tid;
    int v = (i < NN) ? deg[i] : 0;
    s[tid] = v;
    __syncthreads();
    for (int d = 1; d < 256; d <<= 1) {
        int t = (tid >= d) ? s[tid - d] : 0;
        __syncthreads();
        s[tid] += t;
        __syncthreads();
    }
    int excl = bsum[blockIdx.x] + s[tid] - v;
    if (i < NN) { off[i] = excl; deg[i] = excl; }   // deg becomes cursor
    if (i == 0) off[NN] = NE;
}

__global__ __launch_bounds__(256) void k_fill(const int* __restrict__ src, const int* __restrict__ dst,
                                              const float* __restrict__ dinv,
                                              int* __restrict__ cursor, int2* __restrict__ epair) {
    int e = blockIdx.x * 256 + threadIdx.x;
    if (e >= NE) return;
    int s = src[e], d = dst[e];
    int p = atomicAdd(&cursor[d], 1);
    epair[p] = make_int2(s, __float_as_int(dinv[s] * dinv[d]));
}

// ================= bf16 MFMA GEMM: Cb[N,128] = Xb[N,128] @ Wt^T =================
// 256 thr = 4 waves, 16 rows/wave, 64 rows/block. No LDS, no barriers.
// A-frag: A[m=lane&15][k=quad*8+j]  ->  Xb[row][kk*32 + quad*8 ..+7] (16B load)
// B-frag: B[k=quad*8+j][n=lane&15]  ->  Wt[n][kk*32 + quad*8 ..+7]  (16B load)
// D: col=lane&15, row=quad*4+reg.
__global__ __launch_bounds__(256) void k_gemm(const unsigned short* __restrict__ Xb,
                                              const unsigned short* __restrict__ Wt,
                                              unsigned short* __restrict__ Cb, int N) {
    int wave = threadIdx.x >> 6, lane = threadIdx.x & 63;
    int quad = lane >> 4, l16 = lane & 15;
    int row0 = blockIdx.x * 64 + wave * 16;
    int arow = row0 + l16;
    int arc  = arow < N ? arow : N - 1;          // clamp (stores guarded)

    const s8v* xp = (const s8v*)(Xb + (size_t)arc * 128);
    s8v a0 = xp[quad], a1 = xp[4 + quad], a2 = xp[8 + quad], a3 = xp[12 + quad];

    f4v acc[8];
#pragma unroll
    for (int c = 0; c < 8; ++c) acc[c] = (f4v)0.f;

#pragma unroll
    for (int c = 0; c < 8; ++c) {
        const s8v* wp = (const s8v*)(Wt + (size_t)(c * 16 + l16) * 128);
        acc[c] = __builtin_amdgcn_mfma_f32_16x16x32_bf16(a0, wp[quad],      acc[c], 0, 0, 0);
        acc[c] = __builtin_amdgcn_mfma_f32_16x16x32_bf16(a1, wp[4 + quad],  acc[c], 0, 0, 0);
        acc[c] = __builtin_amdgcn_mfma_f32_16x16x32_bf16(a2, wp[8 + quad],  acc[c], 0, 0, 0);
        acc[c] = __builtin_amdgcn_mfma_f32_16x16x32_bf16(a3, wp[12 + quad], acc[c], 0, 0, 0);
    }

#pragma unroll
    for (int c = 0; c < 8; ++c) {
#pragma unroll
        for (int r = 0; r < 4; ++r) {
            int ro = row0 + quad * 4 + r;
            if (ro < N) Cb[(size_t)ro * 128 + c * 16 + l16] = (unsigned short)f2bf(acc[c][r]);
        }
    }
}

// ================= final: [mu|lv] = Xb @ Wtf^T + bias, fp32 packed out =================
__global__ __launch_bounds__(256) void k_final(const unsigned short* __restrict__ Xb,
                                               const unsigned short* __restrict__ Wt,
                                               const float* __restrict__ bmu, const float* __restrict__ blv,
                                               float* __restrict__ out, int N) {
    int wave = threadIdx.x >> 6, lane = threadIdx.x & 63;
    int quad = lane >> 4, l16 = lane & 15;
    int row0 = blockIdx.x * 64 + wave * 16;
    int arow = row0 + l16;
    int arc  = arow < N ? arow : N - 1;

    const s8v* xp = (const s8v*)(Xb + (size_t)arc * 128);
    s8v a0 = xp[quad], a1 = xp[4 + quad], a2 = xp[8 + quad], a3 = xp[12 + quad];

    f4v acc[8];
#pragma unroll
    for (int c = 0; c < 8; ++c) acc[c] = (f4v)0.f;

#pragma unroll
    for (int c = 0; c < 8; ++c) {
        const s8v* wp = (const s8v*)(Wt + (size_t)(c * 16 + l16) * 128);
        acc[c] = __builtin_amdgcn_mfma_f32_16x16x32_bf16(a0, wp[quad],      acc[c], 0, 0, 0);
        acc[c] = __builtin_amdgcn_mfma_f32_16x16x32_bf16(a1, wp[4 + quad],  acc[c], 0, 0, 0);
        acc[c] = __builtin_amdgcn_mfma_f32_16x16x32_bf16(a2, wp[8 + quad],  acc[c], 0, 0, 0);
        acc[c] = __builtin_amdgcn_mfma_f32_16x16x32_bf16(a3, wp[12 + quad], acc[c], 0, 0, 0);
    }

#pragma unroll
    for (int c = 0; c < 8; ++c) {
        int col  = c * 16 + l16;
        float bb = (col < 64) ? bmu[col] : blv[col - 64];
#pragma unroll
        for (int r = 0; r < 4; ++r) {
            int ro = row0 + quad * 4 + r;
            if (ro < N) {
                float v = acc[c][r] + bb;
                if (col < 64) out[(size_t)ro * 64 + col] = v;
                else          out[(size_t)NN * 64 + (size_t)ro * 64 + (col - 64)] = v;
            }
        }
    }
}

// ================= gather agg (bf16) + self-loop + bias + relu -> bf16 =================
// 1 wave/node; lane = 2 channels (1 dword gather -> 256B/row). Scalar epair stream.
__global__ __launch_bounds__(256) void k_agg(const unsigned short* __restrict__ hb, const int* __restrict__ off,
                                             const int2* __restrict__ epair, const float* __restrict__ dinv,
                                             const float* __restrict__ b, unsigned short* __restrict__ outb) {
    int lane = threadIdx.x & 63;
    int n = blockIdx.x * 4 + (threadIdx.x >> 6);   // grid = 12500 -> n < 50000
    int o0 = __builtin_amdgcn_readfirstlane(off[n]);
    int o1 = __builtin_amdgcn_readfirstlane(off[n + 1]);
    const unsigned* h2 = (const unsigned*)hb;      // 2 bf16 ch per dword

    float ax0 = 0.f, ay0 = 0.f, ax1 = 0.f, ay1 = 0.f;
    float ax2 = 0.f, ay2 = 0.f, ax3 = 0.f, ay3 = 0.f;
    int e = o0;
    for (; e + 8 <= o1; e += 8) {
        int s0 = __builtin_amdgcn_readfirstlane(epair[e + 0].x);
        int s1 = __builtin_amdgcn_readfirstlane(epair[e + 1].x);
        int s2 = __builtin_amdgcn_readfirstlane(epair[e + 2].x);
        int s3 = __builtin_amdgcn_readfirstlane(epair[e + 3].x);
        int s4 = __builtin_amdgcn_readfirstlane(epair[e + 4].x);
        int s5 = __builtin_amdgcn_readfirstlane(epair[e + 5].x);
        int s6 = __builtin_amdgcn_readfirstlane(epair[e + 6].x);
        int s7 = __builtin_amdgcn_readfirstlane(epair[e + 7].x);
        float w0 = __int_as_float(__builtin_amdgcn_readfirstlane(epair[e + 0].y));
        float w1 = __int_as_float(__builtin_amdgcn_readfirstlane(epair[e + 1].y));
        float w2 = __int_as_float(__builtin_amdgcn_readfirstlane(epair[e + 2].y));
        float w3 = __int_as_float(__builtin_amdgcn_readfirstlane(epair[e + 3].y));
        float w4 = __int_as_float(__builtin_amdgcn_readfirstlane(epair[e + 4].y));
        float w5 = __int_as_float(__builtin_amdgcn_readfirstlane(epair[e + 5].y));
        float w6 = __int_as_float(__builtin_amdgcn_readfirstlane(epair[e + 6].y));
        float w7 = __int_as_float(__builtin_amdgcn_readfirstlane(epair[e + 7].y));
        unsigned u0 = h2[s0 * 64 + lane];
        unsigned u1 = h2[s1 * 64 + lane];
        unsigned u2 = h2[s2 * 64 + lane];
        unsigned u3 = h2[s3 * 64 + lane];
        unsigned u4 = h2[s4 * 64 + lane];
        unsigned u5 = h2[s5 * 64 + lane];
        unsigned u6 = h2[s6 * 64 + lane];
        unsigned u7 = h2[s7 * 64 + lane];
        ax0 += bf2f_lo(u0) * w0; ay0 += bf2f_hi(u0) * w0;
        ax1 += bf2f_lo(u1) * w1; ay1 += bf2f_hi(u1) * w1;
        ax2 += bf2f_lo(u2) * w2; ay2 += bf2f_hi(u2) * w2;
        ax3 += bf2f_lo(u3) * w3; ay3 += bf2f_hi(u3) * w3;
        ax0 += bf2f_lo(u4) * w4; ay0 += bf2f_hi(u4) * w4;
        ax1 += bf2f_lo(u5) * w5; ay1 += bf2f_hi(u5) * w5;
        ax2 += bf2f_lo(u6) * w6; ay2 += bf2f_hi(u6) * w6;
        ax3 += bf2f_lo(u7) * w7; ay3 += bf2f_hi(u7) * w7;
    }
    if (e + 4 <= o1) {
        int s0 = __builtin_amdgcn_readfirstlane(epair[e + 0].x);
        int s1 = __builtin_amdgcn_readfirstlane(epair[e + 1].x);
        int s2 = __builtin_amdgcn_readfirstlane(epair[e + 2].x);
        int s3 = __builtin_amdgcn_readfirstlane(epair[e + 3].x);
        float w0 = __int_as_float(__builtin_amdgcn_readfirstlane(epair[e + 0].y));
        float w1 = __int_as_float(__builtin_amdgcn_readfirstlane(epair[e + 1].y));
        float w2 = __int_as_float(__builtin_amdgcn_readfirstlane(epair[e + 2].y));
        float w3 = __int_as_float(__builtin_amdgcn_readfirstlane(epair[e + 3].y));
        unsigned u0 = h2[s0 * 64 + lane];
        unsigned u1 = h2[s1 * 64 + lane];
        unsigned u2 = h2[s2 * 64 + lane];
        unsigned u3 = h2[s3 * 64 + lane];
        ax0 += bf2f_lo(u0) * w0; ay0 += bf2f_hi(u0) * w0;
        ax1 += bf2f_lo(u1) * w1; ay1 += bf2f_hi(u1) * w1;
        ax2 += bf2f_lo(u2) * w2; ay2 += bf2f_hi(u2) * w2;
        ax3 += bf2f_lo(u3) * w3; ay3 += bf2f_hi(u3) * w3;
        e += 4;
    }
    for (; e < o1; ++e) {
        int s0 = __builtin_amdgcn_readfirstlane(epair[e].x);
        float w0 = __int_as_float(__builtin_amdgcn_readfirstlane(epair[e].y));
        unsigned u0 = h2[s0 * 64 + lane];
        ax0 += bf2f_lo(u0) * w0; ay0 += bf2f_hi(u0) * w0;
    }

    float dn = dinv[n];
    float sn = dn * dn;
    unsigned uh = h2[n * 64 + lane];
    float2 bb = ((const float2*)b)[lane];
    float rx = fmaxf((ax0 + ax1) + (ax2 + ax3) + bf2f_lo(uh) * sn + bb.x, 0.f);
    float ry = fmaxf((ay0 + ay1) + (ay2 + ay3) + bf2f_hi(uh) * sn + bb.y, 0.f);
    ((unsigned*)outb)[n * 64 + lane] = (f2bf(ry) << 16) | f2bf(rx);
}

extern "C" void kernel_launch(void* const* d_in, const int* in_sizes, int n_in,
                              void* d_out, int out_size, void* d_ws, size_t ws_size,
                              hipStream_t stream) {
    const float* x    = (const float*)d_in[0];
    const int*   eidx = (const int*)d_in[1];
    const float* W1   = (const float*)d_in[2];
    const float* b1   = (const float*)d_in[3];
    const float* W2   = (const float*)d_in[4];
    const float* b2   = (const float*)d_in[5];
    const float* Wmu  = (const float*)d_in[6];
    const float* bmu  = (const float*)d_in[7];
    const float* Wlv  = (const float*)d_in[8];
    const float* blv  = (const float*)d_in[9];
    float* out = (float*)d_out;

    const int* src = eidx;        // edge_index[0]
    const int* dst = eidx + NE;   // edge_index[1]

    // workspace layout (4-byte units)
    float*          ws    = (float*)d_ws;
    float*          dinv  = ws;                            // 50048
    int*            deg   = (int*)(ws + 50048);            // 50048 (becomes cursor)
    int*            off   = (int*)(ws + 100096);           // 50048
    int*            bsum  = (int*)(ws + 150144);           // 256
    int2*           epair = (int2*)(ws + 150400);          // 800000 int2
    unsigned short* Wt    = (unsigned short*)(ws + 1750400);   // 3*16384 bf16 = 24576 floats
    unsigned short* Xb    = (unsigned short*)(ws + 1775000);   // 6.4M bf16 = 3.2M floats
    unsigned short* Hb    = (unsigned short*)(ws + 4975000);   // 6.4M bf16
    unsigned short* Gb    = (unsigned short*)(ws + 8175000);   // 6.4M bf16 (end ~45.5 MB)

    const int gN  = (NN + 255) / 256;      // 196
    const int gE  = (NE + 255) / 256;      // 3125
    const int gG  = (NN + 63) / 64;        // 782
    const int gA  = NN / 4;                // 12500
    const int gC  = (NN * 32 + 255) / 256; // 6250
    const int gW  = (3 * 16384 + 255) / 256; // 192

    // ---- prep (independent of CSR) ----
    k_cast_x<<<gC, 256, 0, stream>>>((const float4*)x, (uint2*)Xb);
    k_prep_w<<<gW, 256, 0, stream>>>(W1, W2, Wmu, Wlv, Wt);

    // ---- CSR build + norms ----
    k_deg_init<<<gN, 256, 0, stream>>>(deg);
    k_deg_count<<<gE, 256, 0, stream>>>(dst, deg);
    k_dinv<<<gN, 256, 0, stream>>>(deg, dinv);
    k_scan1<<<gN, 256, 0, stream>>>(deg, bsum);
    k_scan2<<<1, 256, 0, stream>>>(bsum, gN);
    k_scan3<<<gN, 256, 0, stream>>>(deg, bsum, off);
    k_fill<<<gE, 256, 0, stream>>>(src, dst, dinv, deg, epair);

    // ---- conv1: Hb = Xb@W1 ; Gb = relu(agg(Hb) + self + b1) ----
    k_gemm<<<gG, 256, 0, stream>>>(Xb, Wt, Hb, NN);
    k_agg<<<gA, 256, 0, stream>>>(Hb, off, epair, dinv, b1, Gb);

    // ---- conv2: Hb = Gb@W2 ; Gb = relu(agg(Hb) + self + b2) ----
    k_gemm<<<gG, 256, 0, stream>>>(Gb, Wt + 16384, Hb, NN);
    k_agg<<<gA, 256, 0, stream>>>(Hb, off, epair, dinv, b2, Gb);

    // ---- final projection ----
    k_final<<<gG, 256, 0, stream>>>(Gb, Wt + 32768, bmu, blv, out, NN);
}

// Round 8
// 323.094 us; speedup vs baseline: 1.6234x; 1.0223x over previous
//
#include <hip/hip_runtime.h>

#define NN 50000
#define NE 800000
#define NSLICE 6250   // NN/8: nodes per XCD slice

typedef short s8v  __attribute__((ext_vector_type(8)));   // 8 bf16 (4 VGPRs)
typedef float f4v  __attribute__((ext_vector_type(4)));   // MFMA acc

__device__ __forceinline__ unsigned f2bf(float f) {       // RNE pack
    unsigned u = __float_as_uint(f);
    return (u + 0x7fffu + ((u >> 16) & 1u)) >> 16;
}
__device__ __forceinline__ float bf2f_lo(unsigned u) { return __uint_as_float(u << 16); }
__device__ __forceinline__ float bf2f_hi(unsigned u) { return __uint_as_float(u & 0xffff0000u); }

// ================= prep: cast x -> bf16 =================
__global__ __launch_bounds__(256) void k_cast_x(const float4* __restrict__ x4, uint2* __restrict__ xb) {
    int i = blockIdx.x * 256 + threadIdx.x;      // 1.6M float4s
    if (i >= NN * 32) return;
    float4 v = x4[i];
    uint2 p;
    p.x = (f2bf(v.y) << 16) | f2bf(v.x);
    p.y = (f2bf(v.w) << 16) | f2bf(v.z);
    xb[i] = p;
}

// prep: Wt[m][n][k] = W_m[k][n] as bf16.  m: 0=W1, 1=W2, 2=[Wmu|Wlv]
__global__ __launch_bounds__(256) void k_prep_w(const float* __restrict__ W1, const float* __restrict__ W2,
                                                const float* __restrict__ Wmu, const float* __restrict__ Wlv,
                                                unsigned short* __restrict__ Wt) {
    int idx = blockIdx.x * 256 + threadIdx.x;    // < 3*16384
    if (idx >= 3 * 16384) return;
    int m = idx >> 14, i = idx & 16383;
    int n = i & 127, k = i >> 7;
    float v;
    if (m == 0)      v = W1[k * 128 + n];
    else if (m == 1) v = W2[k * 128 + n];
    else             v = (n < 64) ? Wmu[k * 64 + n] : Wlv[k * 64 + (n - 64)];
    Wt[m * 16384 + n * 128 + k] = (unsigned short)f2bf(v);
}

// ================= CSR build =================
__global__ __launch_bounds__(256) void k_deg_init(int* deg) {
    int i = blockIdx.x * 256 + threadIdx.x;
    if (i < NN) deg[i] = 0;
}

// XCD-sliced degree count: block b&7 -> slice of 6250 nodes (25KB of deg,
// L2-local); each slice's blocks re-read the full dst stream (L3-served)
// and count only their own nodes -> atomic target lines stay in one L2.
__global__ __launch_bounds__(256) void k_deg_count(const int* __restrict__ dst, int* __restrict__ deg) {
    int xcd = blockIdx.x & 7;
    int e = (blockIdx.x >> 3) * 256 + threadIdx.x;
    if (e >= NE) return;
    int d = dst[e];
    if (d / NSLICE == xcd) atomicAdd(&deg[d], 1);
}

__global__ __launch_bounds__(256) void k_dinv(const int* __restrict__ deg, float* __restrict__ dinv) {
    int i = blockIdx.x * 256 + threadIdx.x;
    if (i < NN) dinv[i] = rsqrtf((float)(deg[i] + 1));   // +1 = self loop
}

__global__ __launch_bounds__(256) void k_scan1(const int* __restrict__ deg, int* __restrict__ bsum) {
    __shared__ int s[256];
    int tid = threadIdx.x;
    int i = blockIdx.x * 256 + tid;
    s[tid] = (i < NN) ? deg[i] : 0;
    __syncthreads();
    for (int d = 128; d > 0; d >>= 1) {
        if (tid < d) s[tid] += s[tid + d];
        __syncthreads();
    }
    if (tid == 0) bsum[blockIdx.x] = s[0];
}

__global__ __launch_bounds__(256) void k_scan2(int* bsum, int nblocks) {
    __shared__ int s[256];
    int tid = threadIdx.x;
    int v = (tid < nblocks) ? bsum[tid] : 0;
    s[tid] = v;
    __syncthreads();
    for (int d = 1; d < 256; d <<= 1) {
        int t = (tid >= d) ? s[tid - d] : 0;
        __syncthreads();
        s[tid] += t;
        __syncthreads();
    }
    if (tid < nblocks) bsum[tid] = s[tid] - v;   // exclusive
}

__global__ __launch_bounds__(256) void k_scan3(int* __restrict__ deg, const int* __restrict__ bsum,
                                               int* __restrict__ off) {
    __shared__ int s[256];
    int tid = threadIdx.x;
    int i = blockIdx.x * 256 + tid;
    int v = (i < NN) ? deg[i] : 0;
    s[tid] = v;
    __syncthreads();
    for (int d = 1; d < 256; d <<= 1) {
        int t = (tid >= d) ? s[tid - d] : 0;
        __syncthreads();
        s[tid] += t;
        __syncthreads();
    }
    int excl = bsum[blockIdx.x] + s[tid] - v;
    if (i < NN) { off[i] = excl; deg[i] = excl; }   // deg becomes cursor
    if (i == 0) off[NN] = NE;
}

// XCD-sliced CSR fill: slice = d/6250 -> each XCD's writes land in a
// contiguous ~800KB epair region that stays resident in its own L2, so
// the 800k scattered 8B writes coalesce to ~6.4MB of HBM writeback
// instead of 51MB of line-RMW.
__global__ __launch_bounds__(256) void k_fill(const int* __restrict__ src, const int* __restrict__ dst,
                                              const float* __restrict__ dinv,
                                              int* __restrict__ cursor, int2* __restrict__ epair) {
    int xcd = blockIdx.x & 7;
    int e = (blockIdx.x >> 3) * 256 + threadIdx.x;
    if (e >= NE) return;
    int d = dst[e];
    if (d / NSLICE != xcd) return;
    int s = src[e];
    int p = atomicAdd(&cursor[d], 1);
    epair[p] = make_int2(s, __float_as_int(dinv[s] * dinv[d]));
}

// ================= bf16 MFMA GEMM: Cb[N,128] = Xb[N,128] @ Wt^T =================
__global__ __launch_bounds__(256) void k_gemm(const unsigned short* __restrict__ Xb,
                                              const unsigned short* __restrict__ Wt,
                                              unsigned short* __restrict__ Cb, int N) {
    int wave = threadIdx.x >> 6, lane = threadIdx.x & 63;
    int quad = lane >> 4, l16 = lane & 15;
    int row0 = blockIdx.x * 64 + wave * 16;
    int arow = row0 + l16;
    int arc  = arow < N ? arow : N - 1;          // clamp (stores guarded)

    const s8v* xp = (const s8v*)(Xb + (size_t)arc * 128);
    s8v a0 = xp[quad], a1 = xp[4 + quad], a2 = xp[8 + quad], a3 = xp[12 + quad];

    f4v acc[8];
#pragma unroll
    for (int c = 0; c < 8; ++c) acc[c] = (f4v)0.f;

#pragma unroll
    for (int c = 0; c < 8; ++c) {
        const s8v* wp = (const s8v*)(Wt + (size_t)(c * 16 + l16) * 128);
        acc[c] = __builtin_amdgcn_mfma_f32_16x16x32_bf16(a0, wp[quad],      acc[c], 0, 0, 0);
        acc[c] = __builtin_amdgcn_mfma_f32_16x16x32_bf16(a1, wp[4 + quad],  acc[c], 0, 0, 0);
        acc[c] = __builtin_amdgcn_mfma_f32_16x16x32_bf16(a2, wp[8 + quad],  acc[c], 0, 0, 0);
        acc[c] = __builtin_amdgcn_mfma_f32_16x16x32_bf16(a3, wp[12 + quad], acc[c], 0, 0, 0);
    }

#pragma unroll
    for (int c = 0; c < 8; ++c) {
#pragma unroll
        for (int r = 0; r < 4; ++r) {
            int ro = row0 + quad * 4 + r;
            if (ro < N) Cb[(size_t)ro * 128 + c * 16 + l16] = (unsigned short)f2bf(acc[c][r]);
        }
    }
}

// ================= final: [mu|lv] = Xb @ Wt^T + bias, fp32 packed out =================
__global__ __launch_bounds__(256) void k_final(const unsigned short* __restrict__ Xb,
                                               const unsigned short* __restrict__ Wt,
                                               const float* __restrict__ bmu, const float* __restrict__ blv,
                                               float* __restrict__ out, int N) {
    int wave = threadIdx.x >> 6, lane = threadIdx.x & 63;
    int quad = lane >> 4, l16 = lane & 15;
    int row0 = blockIdx.x * 64 + wave * 16;
    int arow = row0 + l16;
    int arc  = arow < N ? arow : N - 1;

    const s8v* xp = (const s8v*)(Xb + (size_t)arc * 128);
    s8v a0 = xp[quad], a1 = xp[4 + quad], a2 = xp[8 + quad], a3 = xp[12 + quad];

    f4v acc[8];
#pragma unroll
    for (int c = 0; c < 8; ++c) acc[c] = (f4v)0.f;

#pragma unroll
    for (int c = 0; c < 8; ++c) {
        const s8v* wp = (const s8v*)(Wt + (size_t)(c * 16 + l16) * 128);
        acc[c] = __builtin_amdgcn_mfma_f32_16x16x32_bf16(a0, wp[quad],      acc[c], 0, 0, 0);
        acc[c] = __builtin_amdgcn_mfma_f32_16x16x32_bf16(a1, wp[4 + quad],  acc[c], 0, 0, 0);
        acc[c] = __builtin_amdgcn_mfma_f32_16x16x32_bf16(a2, wp[8 + quad],  acc[c], 0, 0, 0);
        acc[c] = __builtin_amdgcn_mfma_f32_16x16x32_bf16(a3, wp[12 + quad], acc[c], 0, 0, 0);
    }

#pragma unroll
    for (int c = 0; c < 8; ++c) {
        int col  = c * 16 + l16;
        float bb = (col < 64) ? bmu[col] : blv[col - 64];
#pragma unroll
        for (int r = 0; r < 4; ++r) {
            int ro = row0 + quad * 4 + r;
            if (ro < N) {
                float v = acc[c][r] + bb;
                if (col < 64) out[(size_t)ro * 64 + col] = v;
                else          out[(size_t)NN * 64 + (size_t)ro * 64 + (col - 64)] = v;
            }
        }
    }
}

// ================= gather agg (bf16) + self-loop + bias + relu -> bf16 =================
// 1 wave/node; lane = 2 channels (1 dword gather -> 256B/row). Scalar epair stream.
__global__ __launch_bounds__(256) void k_agg(const unsigned short* __restrict__ hb, const int* __restrict__ off,
                                             const int2* __restrict__ epair, const float* __restrict__ dinv,
                                             const float* __restrict__ b, unsigned short* __restrict__ outb) {
    int lane = threadIdx.x & 63;
    int n = blockIdx.x * 4 + (threadIdx.x >> 6);   // grid = 12500 -> n < 50000
    int o0 = __builtin_amdgcn_readfirstlane(off[n]);
    int o1 = __builtin_amdgcn_readfirstlane(off[n + 1]);
    const unsigned* h2 = (const unsigned*)hb;      // 2 bf16 ch per dword

    float ax0 = 0.f, ay0 = 0.f, ax1 = 0.f, ay1 = 0.f;
    float ax2 = 0.f, ay2 = 0.f, ax3 = 0.f, ay3 = 0.f;
    int e = o0;
    for (; e + 8 <= o1; e += 8) {
        int s0 = __builtin_amdgcn_readfirstlane(epair[e + 0].x);
        int s1 = __builtin_amdgcn_readfirstlane(epair[e + 1].x);
        int s2 = __builtin_amdgcn_readfirstlane(epair[e + 2].x);
        int s3 = __builtin_amdgcn_readfirstlane(epair[e + 3].x);
        int s4 = __builtin_amdgcn_readfirstlane(epair[e + 4].x);
        int s5 = __builtin_amdgcn_readfirstlane(epair[e + 5].x);
        int s6 = __builtin_amdgcn_readfirstlane(epair[e + 6].x);
        int s7 = __builtin_amdgcn_readfirstlane(epair[e + 7].x);
        float w0 = __int_as_float(__builtin_amdgcn_readfirstlane(epair[e + 0].y));
        float w1 = __int_as_float(__builtin_amdgcn_readfirstlane(epair[e + 1].y));
        float w2 = __int_as_float(__builtin_amdgcn_readfirstlane(epair[e + 2].y));
        float w3 = __int_as_float(__builtin_amdgcn_readfirstlane(epair[e + 3].y));
        float w4 = __int_as_float(__builtin_amdgcn_readfirstlane(epair[e + 4].y));
        float w5 = __int_as_float(__builtin_amdgcn_readfirstlane(epair[e + 5].y));
        float w6 = __int_as_float(__builtin_amdgcn_readfirstlane(epair[e + 6].y));
        float w7 = __int_as_float(__builtin_amdgcn_readfirstlane(epair[e + 7].y));
        unsigned u0 = h2[s0 * 64 + lane];
        unsigned u1 = h2[s1 * 64 + lane];
        unsigned u2 = h2[s2 * 64 + lane];
        unsigned u3 = h2[s3 * 64 + lane];
        unsigned u4 = h2[s4 * 64 + lane];
        unsigned u5 = h2[s5 * 64 + lane];
        unsigned u6 = h2[s6 * 64 + lane];
        unsigned u7 = h2[s7 * 64 + lane];
        ax0 += bf2f_lo(u0) * w0; ay0 += bf2f_hi(u0) * w0;
        ax1 += bf2f_lo(u1) * w1; ay1 += bf2f_hi(u1) * w1;
        ax2 += bf2f_lo(u2) * w2; ay2 += bf2f_hi(u2) * w2;
        ax3 += bf2f_lo(u3) * w3; ay3 += bf2f_hi(u3) * w3;
        ax0 += bf2f_lo(u4) * w4; ay0 += bf2f_hi(u4) * w4;
        ax1 += bf2f_lo(u5) * w5; ay1 += bf2f_hi(u5) * w5;
        ax2 += bf2f_lo(u6) * w6; ay2 += bf2f_hi(u6) * w6;
        ax3 += bf2f_lo(u7) * w7; ay3 += bf2f_hi(u7) * w7;
    }
    if (e + 4 <= o1) {
        int s0 = __builtin_amdgcn_readfirstlane(epair[e + 0].x);
        int s1 = __builtin_amdgcn_readfirstlane(epair[e + 1].x);
        int s2 = __builtin_amdgcn_readfirstlane(epair[e + 2].x);
        int s3 = __builtin_amdgcn_readfirstlane(epair[e + 3].x);
        float w0 = __int_as_float(__builtin_amdgcn_readfirstlane(epair[e + 0].y));
        float w1 = __int_as_float(__builtin_amdgcn_readfirstlane(epair[e + 1].y));
        float w2 = __int_as_float(__builtin_amdgcn_readfirstlane(epair[e + 2].y));
        float w3 = __int_as_float(__builtin_amdgcn_readfirstlane(epair[e + 3].y));
        unsigned u0 = h2[s0 * 64 + lane];
        unsigned u1 = h2[s1 * 64 + lane];
        unsigned u2 = h2[s2 * 64 + lane];
        unsigned u3 = h2[s3 * 64 + lane];
        ax0 += bf2f_lo(u0) * w0; ay0 += bf2f_hi(u0) * w0;
        ax1 += bf2f_lo(u1) * w1; ay1 += bf2f_hi(u1) * w1;
        ax2 += bf2f_lo(u2) * w2; ay2 += bf2f_hi(u2) * w2;
        ax3 += bf2f_lo(u3) * w3; ay3 += bf2f_hi(u3) * w3;
        e += 4;
    }
    for (; e < o1; ++e) {
        int s0 = __builtin_amdgcn_readfirstlane(epair[e].x);
        float w0 = __int_as_float(__builtin_amdgcn_readfirstlane(epair[e].y));
        unsigned u0 = h2[s0 * 64 + lane];
        ax0 += bf2f_lo(u0) * w0; ay0 += bf2f_hi(u0) * w0;
    }

    float dn = dinv[n];
    float sn = dn * dn;
    unsigned uh = h2[n * 64 + lane];
    float2 bb = ((const float2*)b)[lane];
    float rx = fmaxf((ax0 + ax1) + (ax2 + ax3) + bf2f_lo(uh) * sn + bb.x, 0.f);
    float ry = fmaxf((ay0 + ay1) + (ay2 + ay3) + bf2f_hi(uh) * sn + bb.y, 0.f);
    ((unsigned*)outb)[n * 64 + lane] = (f2bf(ry) << 16) | f2bf(rx);
}

extern "C" void kernel_launch(void* const* d_in, const int* in_sizes, int n_in,
                              void* d_out, int out_size, void* d_ws, size_t ws_size,
                              hipStream_t stream) {
    const float* x    = (const float*)d_in[0];
    const int*   eidx = (const int*)d_in[1];
    const float* W1   = (const float*)d_in[2];
    const float* b1   = (const float*)d_in[3];
    const float* W2   = (const float*)d_in[4];
    const float* b2   = (const float*)d_in[5];
    const float* Wmu  = (const float*)d_in[6];
    const float* bmu  = (const float*)d_in[7];
    const float* Wlv  = (const float*)d_in[8];
    const float* blv  = (const float*)d_in[9];
    float* out = (float*)d_out;

    const int* src = eidx;        // edge_index[0]
    const int* dst = eidx + NE;   // edge_index[1]

    // workspace layout (4-byte units)
    float*          ws    = (float*)d_ws;
    float*          dinv  = ws;                            // 50048
    int*            deg   = (int*)(ws + 50048);            // 50048 (becomes cursor)
    int*            off   = (int*)(ws + 100096);           // 50048
    int*            bsum  = (int*)(ws + 150144);           // 256
    int2*           epair = (int2*)(ws + 150400);          // 800000 int2
    unsigned short* Wt    = (unsigned short*)(ws + 1750400);   // 3*16384 bf16
    unsigned short* Xb    = (unsigned short*)(ws + 1775000);   // 6.4M bf16
    unsigned short* Hb    = (unsigned short*)(ws + 4975000);   // 6.4M bf16
    unsigned short* Gb    = (unsigned short*)(ws + 8175000);   // 6.4M bf16

    const int gN  = (NN + 255) / 256;        // 196
    const int gE  = (NE + 255) / 256;        // 3125
    const int gE8 = gE * 8;                  // 25000 (XCD-sliced passes)
    const int gG  = (NN + 63) / 64;          // 782
    const int gA  = NN / 4;                  // 12500
    const int gC  = (NN * 32 + 255) / 256;   // 6250
    const int gW  = (3 * 16384 + 255) / 256; // 192

    // ---- prep (independent of CSR) ----
    k_cast_x<<<gC, 256, 0, stream>>>((const float4*)x, (uint2*)Xb);
    k_prep_w<<<gW, 256, 0, stream>>>(W1, W2, Wmu, Wlv, Wt);

    // ---- CSR build + norms ----
    k_deg_init<<<gN, 256, 0, stream>>>(deg);
    k_deg_count<<<gE8, 256, 0, stream>>>(dst, deg);
    k_dinv<<<gN, 256, 0, stream>>>(deg, dinv);
    k_scan1<<<gN, 256, 0, stream>>>(deg, bsum);
    k_scan2<<<1, 256, 0, stream>>>(bsum, gN);
    k_scan3<<<gN, 256, 0, stream>>>(deg, bsum, off);
    k_fill<<<gE8, 256, 0, stream>>>(src, dst, dinv, deg, epair);

    // ---- conv1: Hb = Xb@W1 ; Gb = relu(agg(Hb) + self + b1) ----
    k_gemm<<<gG, 256, 0, stream>>>(Xb, Wt, Hb, NN);
    k_agg<<<gA, 256, 0, stream>>>(Hb, off, epair, dinv, b1, Gb);

    // ---- conv2: Hb = Gb@W2 ; Gb = relu(agg(Hb) + self + b2) ----
    k_gemm<<<gG, 256, 0, stream>>>(Gb, Wt + 16384, Hb, NN);
    k_agg<<<gA, 256, 0, stream>>>(Hb, off, epair, dinv, b2, Gb);

    // ---- final projection ----
    k_final<<<gG, 256, 0, stream>>>(Gb, Wt + 32768, bmu, blv, out, NN);
}

// Round 9
// 318.157 us; speedup vs baseline: 1.6486x; 1.0155x over previous
//
#include <hip/hip_runtime.h>

#define NN 50000
#define NE 800000
#define NSLICE 6250   // NN/8: nodes per XCD slice

typedef short s8v  __attribute__((ext_vector_type(8)));   // 8 bf16 (4 VGPRs)
typedef float f4v  __attribute__((ext_vector_type(4)));   // MFMA acc

__device__ __forceinline__ unsigned f2bf(float f) {       // RNE pack
    unsigned u = __float_as_uint(f);
    return (u + 0x7fffu + ((u >> 16) & 1u)) >> 16;
}
__device__ __forceinline__ float bf2f_lo(unsigned u) { return __uint_as_float(u << 16); }
__device__ __forceinline__ float bf2f_hi(unsigned u) { return __uint_as_float(u & 0xffff0000u); }

// ================= fused prep: cast x -> bf16 | transpose W -> bf16 | deg=0 =================
// blocks [0,6250): cast x; [6250,6442): Wt; [6442,6638): deg_init
__global__ __launch_bounds__(256) void k_prep(const float4* __restrict__ x4, uint2* __restrict__ xb,
                                              const float* __restrict__ W1, const float* __restrict__ W2,
                                              const float* __restrict__ Wmu, const float* __restrict__ Wlv,
                                              unsigned short* __restrict__ Wt, int* __restrict__ deg) {
    int b = blockIdx.x;
    if (b < 6250) {
        int i = b * 256 + threadIdx.x;
        if (i >= NN * 32) return;
        float4 v = x4[i];
        uint2 p;
        p.x = (f2bf(v.y) << 16) | f2bf(v.x);
        p.y = (f2bf(v.w) << 16) | f2bf(v.z);
        xb[i] = p;
    } else if (b < 6442) {
        int idx = (b - 6250) * 256 + threadIdx.x;
        if (idx >= 3 * 16384) return;
        int m = idx >> 14, i = idx & 16383;
        int n = i & 127, k = i >> 7;
        float v;
        if (m == 0)      v = W1[k * 128 + n];
        else if (m == 1) v = W2[k * 128 + n];
        else             v = (n < 64) ? Wmu[k * 64 + n] : Wlv[k * 64 + (n - 64)];
        Wt[m * 16384 + n * 128 + k] = (unsigned short)f2bf(v);
    } else {
        int i = (b - 6442) * 256 + threadIdx.x;
        if (i < NN) deg[i] = 0;
    }
}

// XCD-sliced degree count (block b&7 -> node slice, atomic targets stay in one L2)
__global__ __launch_bounds__(256) void k_deg_count(const int* __restrict__ dst, int* __restrict__ deg) {
    int xcd = blockIdx.x & 7;
    int e = (blockIdx.x >> 3) * 256 + threadIdx.x;
    if (e >= NE) return;
    int d = dst[e];
    if (d / NSLICE == xcd) atomicAdd(&deg[d], 1);
}

// scan pass 1 (+ fused dinv)
__global__ __launch_bounds__(256) void k_scan1(const int* __restrict__ deg, int* __restrict__ bsum,
                                               float* __restrict__ dinv) {
    __shared__ int s[256];
    int tid = threadIdx.x;
    int i = blockIdx.x * 256 + tid;
    int v = (i < NN) ? deg[i] : 0;
    s[tid] = v;
    if (i < NN) dinv[i] = rsqrtf((float)(v + 1));   // +1 = self loop
    __syncthreads();
    for (int d = 128; d > 0; d >>= 1) {
        if (tid < d) s[tid] += s[tid + d];
        __syncthreads();
    }
    if (tid == 0) bsum[blockIdx.x] = s[0];
}

__global__ __launch_bounds__(256) void k_scan2(int* bsum, int nblocks) {
    __shared__ int s[256];
    int tid = threadIdx.x;
    int v = (tid < nblocks) ? bsum[tid] : 0;
    s[tid] = v;
    __syncthreads();
    for (int d = 1; d < 256; d <<= 1) {
        int t = (tid >= d) ? s[tid - d] : 0;
        __syncthreads();
        s[tid] += t;
        __syncthreads();
    }
    if (tid < nblocks) bsum[tid] = s[tid] - v;   // exclusive
}

__global__ __launch_bounds__(256) void k_scan3(int* __restrict__ deg, const int* __restrict__ bsum,
                                               int* __restrict__ off) {
    __shared__ int s[256];
    int tid = threadIdx.x;
    int i = blockIdx.x * 256 + tid;
    int v = (i < NN) ? deg[i] : 0;
    s[tid] = v;
    __syncthreads();
    for (int d = 1; d < 256; d <<= 1) {
        int t = (tid >= d) ? s[tid - d] : 0;
        __syncthreads();
        s[tid] += t;
        __syncthreads();
    }
    int excl = bsum[blockIdx.x] + s[tid] - v;
    if (i < NN) { off[i] = excl; deg[i] = excl; }   // deg becomes cursor
    if (i == 0) off[NN] = NE;
}

// XCD-sliced CSR fill (slice's ~800KB epair region stays in its XCD's L2)
__global__ __launch_bounds__(256) void k_fill(const int* __restrict__ src, const int* __restrict__ dst,
                                              const float* __restrict__ dinv,
                                              int* __restrict__ cursor, int2* __restrict__ epair) {
    int xcd = blockIdx.x & 7;
    int e = (blockIdx.x >> 3) * 256 + threadIdx.x;
    if (e >= NE) return;
    int d = dst[e];
    if (d / NSLICE != xcd) return;
    int s = src[e];
    int p = atomicAdd(&cursor[d], 1);
    epair[p] = make_int2(s, __float_as_int(dinv[s] * dinv[d]));
}

// ================= bf16 MFMA GEMM: Cb[N,128] = Xb[N,128] @ Wt^T =================
__global__ __launch_bounds__(256) void k_gemm(const unsigned short* __restrict__ Xb,
                                              const unsigned short* __restrict__ Wt,
                                              unsigned short* __restrict__ Cb, int N) {
    int wave = threadIdx.x >> 6, lane = threadIdx.x & 63;
    int quad = lane >> 4, l16 = lane & 15;
    int row0 = blockIdx.x * 64 + wave * 16;
    int arow = row0 + l16;
    int arc  = arow < N ? arow : N - 1;          // clamp (stores guarded)

    const s8v* xp = (const s8v*)(Xb + (size_t)arc * 128);
    s8v a0 = xp[quad], a1 = xp[4 + quad], a2 = xp[8 + quad], a3 = xp[12 + quad];

    f4v acc[8];
#pragma unroll
    for (int c = 0; c < 8; ++c) acc[c] = (f4v)0.f;

#pragma unroll
    for (int c = 0; c < 8; ++c) {
        const s8v* wp = (const s8v*)(Wt + (size_t)(c * 16 + l16) * 128);
        acc[c] = __builtin_amdgcn_mfma_f32_16x16x32_bf16(a0, wp[quad],      acc[c], 0, 0, 0);
        acc[c] = __builtin_amdgcn_mfma_f32_16x16x32_bf16(a1, wp[4 + quad],  acc[c], 0, 0, 0);
        acc[c] = __builtin_amdgcn_mfma_f32_16x16x32_bf16(a2, wp[8 + quad],  acc[c], 0, 0, 0);
        acc[c] = __builtin_amdgcn_mfma_f32_16x16x32_bf16(a3, wp[12 + quad], acc[c], 0, 0, 0);
    }

#pragma unroll
    for (int c = 0; c < 8; ++c) {
#pragma unroll
        for (int r = 0; r < 4; ++r) {
            int ro = row0 + quad * 4 + r;
            if (ro < N) Cb[(size_t)ro * 128 + c * 16 + l16] = (unsigned short)f2bf(acc[c][r]);
        }
    }
}

// ================= final: [mu|lv] = Xb @ Wt^T + bias, fp32 packed out =================
__global__ __launch_bounds__(256) void k_final(const unsigned short* __restrict__ Xb,
                                               const unsigned short* __restrict__ Wt,
                                               const float* __restrict__ bmu, const float* __restrict__ blv,
                                               float* __restrict__ out, int N) {
    int wave = threadIdx.x >> 6, lane = threadIdx.x & 63;
    int quad = lane >> 4, l16 = lane & 15;
    int row0 = blockIdx.x * 64 + wave * 16;
    int arow = row0 + l16;
    int arc  = arow < N ? arow : N - 1;

    const s8v* xp = (const s8v*)(Xb + (size_t)arc * 128);
    s8v a0 = xp[quad], a1 = xp[4 + quad], a2 = xp[8 + quad], a3 = xp[12 + quad];

    f4v acc[8];
#pragma unroll
    for (int c = 0; c < 8; ++c) acc[c] = (f4v)0.f;

#pragma unroll
    for (int c = 0; c < 8; ++c) {
        const s8v* wp = (const s8v*)(Wt + (size_t)(c * 16 + l16) * 128);
        acc[c] = __builtin_amdgcn_mfma_f32_16x16x32_bf16(a0, wp[quad],      acc[c], 0, 0, 0);
        acc[c] = __builtin_amdgcn_mfma_f32_16x16x32_bf16(a1, wp[4 + quad],  acc[c], 0, 0, 0);
        acc[c] = __builtin_amdgcn_mfma_f32_16x16x32_bf16(a2, wp[8 + quad],  acc[c], 0, 0, 0);
        acc[c] = __builtin_amdgcn_mfma_f32_16x16x32_bf16(a3, wp[12 + quad], acc[c], 0, 0, 0);
    }

#pragma unroll
    for (int c = 0; c < 8; ++c) {
        int col  = c * 16 + l16;
        float bb = (col < 64) ? bmu[col] : blv[col - 64];
#pragma unroll
        for (int r = 0; r < 4; ++r) {
            int ro = row0 + quad * 4 + r;
            if (ro < N) {
                float v = acc[c][r] + bb;
                if (col < 64) out[(size_t)ro * 64 + col] = v;
                else          out[(size_t)NN * 64 + (size_t)ro * 64 + (col - 64)] = v;
            }
        }
    }
}

// ================= gather agg (bf16) + self-loop + bias + relu -> bf16 =================
// 1 wave/node. Masked straight-line 24-gather prologue: 24 independent gathers
// in flight (96B/lane) regardless of degree (masked edges read epair[0]/h row 0
// -> L1 hits, weight forced 0). deg>24 (P~2%) continues in masked 8-batches.
// NO serial per-edge loop anywhere. Weights/indices ride in SGPRs.
__global__ __launch_bounds__(256) void k_agg(const unsigned short* __restrict__ hb, const int* __restrict__ off,
                                             const int2* __restrict__ epair, const float* __restrict__ dinv,
                                             const float* __restrict__ b, unsigned short* __restrict__ outb) {
    int lane = threadIdx.x & 63;
    int n = blockIdx.x * 4 + (threadIdx.x >> 6);   // grid = 12500 -> n < 50000
    int o0 = __builtin_amdgcn_readfirstlane(off[n]);
    int o1 = __builtin_amdgcn_readfirstlane(off[n + 1]);
    int d  = o1 - o0;
    const unsigned* h2 = (const unsigned*)hb;      // 2 bf16 ch per dword

    float ax0 = 0.f, ay0 = 0.f, ax1 = 0.f, ay1 = 0.f;
    float ax2 = 0.f, ay2 = 0.f, ax3 = 0.f, ay3 = 0.f;

    {   // prologue: 24 masked gathers, all independent
        unsigned u[24];
        float    w[24];
#pragma unroll
        for (int k = 0; k < 24; ++k) {
            int idx = (k < d) ? (o0 + k) : 0;
            int s   = __builtin_amdgcn_readfirstlane(epair[idx].x);
            float wk = __int_as_float(__builtin_amdgcn_readfirstlane(epair[idx].y));
            w[k] = (k < d) ? wk : 0.f;
            u[k] = h2[(size_t)s * 64 + lane];
        }
#pragma unroll
        for (int k = 0; k < 24; ++k) {
            float lo = bf2f_lo(u[k]), hi = bf2f_hi(u[k]);
            switch (k & 3) {
                case 0: ax0 += lo * w[k]; ay0 += hi * w[k]; break;
                case 1: ax1 += lo * w[k]; ay1 += hi * w[k]; break;
                case 2: ax2 += lo * w[k]; ay2 += hi * w[k]; break;
                default: ax3 += lo * w[k]; ay3 += hi * w[k]; break;
            }
        }
    }

    // epilogue loop: masked 8-batches for deg > 24
    for (int e = o0 + 24; e < o1; e += 8) {
        unsigned u[8];
        float    w[8];
#pragma unroll
        for (int k = 0; k < 8; ++k) {
            int ek  = e + k;
            int idx = (ek < o1) ? ek : 0;
            int s   = __builtin_amdgcn_readfirstlane(epair[idx].x);
            float wk = __int_as_float(__builtin_amdgcn_readfirstlane(epair[idx].y));
            w[k] = (ek < o1) ? wk : 0.f;
            u[k] = h2[(size_t)s * 64 + lane];
        }
#pragma unroll
        for (int k = 0; k < 8; ++k) {
            float lo = bf2f_lo(u[k]), hi = bf2f_hi(u[k]);
            switch (k & 3) {
                case 0: ax0 += lo * w[k]; ay0 += hi * w[k]; break;
                case 1: ax1 += lo * w[k]; ay1 += hi * w[k]; break;
                case 2: ax2 += lo * w[k]; ay2 += hi * w[k]; break;
                default: ax3 += lo * w[k]; ay3 += hi * w[k]; break;
            }
        }
    }

    float dn = dinv[n];
    float sn = dn * dn;
    unsigned uh = h2[n * 64 + lane];
    float2 bb = ((const float2*)b)[lane];
    float rx = fmaxf((ax0 + ax1) + (ax2 + ax3) + bf2f_lo(uh) * sn + bb.x, 0.f);
    float ry = fmaxf((ay0 + ay1) + (ay2 + ay3) + bf2f_hi(uh) * sn + bb.y, 0.f);
    ((unsigned*)outb)[n * 64 + lane] = (f2bf(ry) << 16) | f2bf(rx);
}

extern "C" void kernel_launch(void* const* d_in, const int* in_sizes, int n_in,
                              void* d_out, int out_size, void* d_ws, size_t ws_size,
                              hipStream_t stream) {
    const float* x    = (const float*)d_in[0];
    const int*   eidx = (const int*)d_in[1];
    const float* W1   = (const float*)d_in[2];
    const float* b1   = (const float*)d_in[3];
    const float* W2   = (const float*)d_in[4];
    const float* b2   = (const float*)d_in[5];
    const float* Wmu  = (const float*)d_in[6];
    const float* bmu  = (const float*)d_in[7];
    const float* Wlv  = (const float*)d_in[8];
    const float* blv  = (const float*)d_in[9];
    float* out = (float*)d_out;

    const int* src = eidx;        // edge_index[0]
    const int* dst = eidx + NE;   // edge_index[1]

    // workspace layout (4-byte units)
    float*          ws    = (float*)d_ws;
    float*          dinv  = ws;                            // 50048
    int*            deg   = (int*)(ws + 50048);            // 50048 (becomes cursor)
    int*            off   = (int*)(ws + 100096);           // 50048
    int*            bsum  = (int*)(ws + 150144);           // 256
    int2*           epair = (int2*)(ws + 150400);          // 800000 int2
    unsigned short* Wt    = (unsigned short*)(ws + 1750400);   // 3*16384 bf16
    unsigned short* Xb    = (unsigned short*)(ws + 1775000);   // 6.4M bf16
    unsigned short* Hb    = (unsigned short*)(ws + 4975000);   // 6.4M bf16
    unsigned short* Gb    = (unsigned short*)(ws + 8175000);   // 6.4M bf16

    const int gN  = (NN + 255) / 256;        // 196
    const int gE8 = ((NE + 255) / 256) * 8;  // 25000 (XCD-sliced passes)
    const int gG  = (NN + 63) / 64;          // 782
    const int gA  = NN / 4;                  // 12500
    const int gP  = 6250 + 192 + 196;        // fused prep grid

    // ---- fused prep: cast x, transpose W, zero deg ----
    k_prep<<<gP, 256, 0, stream>>>((const float4*)x, (uint2*)Xb, W1, W2, Wmu, Wlv, Wt, deg);

    // ---- CSR build + norms ----
    k_deg_count<<<gE8, 256, 0, stream>>>(dst, deg);
    k_scan1<<<gN, 256, 0, stream>>>(deg, bsum, dinv);
    k_scan2<<<1, 256, 0, stream>>>(bsum, gN);
    k_scan3<<<gN, 256, 0, stream>>>(deg, bsum, off);
    k_fill<<<gE8, 256, 0, stream>>>(src, dst, dinv, deg, epair);

    // ---- conv1: Hb = Xb@W1 ; Gb = relu(agg(Hb) + self + b1) ----
    k_gemm<<<gG, 256, 0, stream>>>(Xb, Wt, Hb, NN);
    k_agg<<<gA, 256, 0, stream>>>(Hb, off, epair, dinv, b1, Gb);

    // ---- conv2: Hb = Gb@W2 ; Gb = relu(agg(Hb) + self + b2) ----
    k_gemm<<<gG, 256, 0, stream>>>(Gb, Wt + 16384, Hb, NN);
    k_agg<<<gA, 256, 0, stream>>>(Hb, off, epair, dinv, b2, Gb);

    // ---- final projection ----
    k_final<<<gG, 256, 0, stream>>>(Gb, Wt + 32768, bmu, blv, out, NN);
}